// Round 4
// baseline (94.231 us; speedup 1.0000x reference)
//
#include <hip/hip_runtime.h>
#include <math.h>

#define NQ 12
#define TPB 256

// One 256-thread block (4 waves) per sample. 4096-amp state split 4-way:
// each thread holds v[16] float2. Three register layouts over amp index j
// (qubit q <-> j bit 11-q):
//   A: j = (r<<8)|t   r = j bits  8..11 = qubits 0..3
//   B: j = (thi<<8)|(r<<4)|tlo   r = j bits 4..7 = qubits 4..7
//   C: j = (t<<4)|r   r = j bits  0..3 = qubits 8..11
// LDS holds amp j at phys(j) = (j&~15) | ((j ^ (j>>4) ^ (j>>8)) & 15)
// (XOR swizzle -> all transpose/scatter patterns conflict-free).
// Circuit (after algebraic reduction):
//   init = layer-0 RX product state with ring perm FOLDED (inverse perm),
//   12 fused RZ*RY, 12 RX, ring scatter, 12 RY (final RZ dropped), measure.
// Schedule: [init+G0-3]A ->T-> [G4-7]B ->T-> [G8-11,RX8-11]C ->T-> [RX4-7]B
//   ->T-> [RX0-3]A ->RING-> [RY8-11]C ->T-> [RY4-7]B ->T-> [RY0-3,meas]A

__device__ __forceinline__ void g_fused(float2& a0, float2& a1,
    float g00x, float g00y, float g01x, float g01y,
    float g10x, float g10y, float g11x, float g11y)
{
    float n0x = g00x*a0.x - g00y*a0.y + g01x*a1.x - g01y*a1.y;
    float n0y = g00x*a0.y + g00y*a0.x + g01x*a1.y + g01y*a1.x;
    float n1x = g10x*a0.x - g10y*a0.y + g11x*a1.x - g11y*a1.y;
    float n1y = g10x*a0.y + g10y*a0.x + g11x*a1.y + g11y*a1.x;
    a0.x = n0x; a0.y = n0y; a1.x = n1x; a1.y = n1y;
}

__device__ __forceinline__ void g_rx(float2& a0, float2& a1, float c, float s)
{
    float n0x = c*a0.x + s*a1.y;
    float n0y = c*a0.y - s*a1.x;
    float n1x = c*a1.x + s*a0.y;
    float n1y = c*a1.y - s*a0.x;
    a0.x = n0x; a0.y = n0y; a1.x = n1x; a1.y = n1y;
}

__device__ __forceinline__ void g_ry(float2& a0, float2& a1, float c, float s)
{
    float n0x = c*a0.x - s*a1.x;
    float n0y = c*a0.y - s*a1.y;
    float n1x = s*a0.x + c*a1.x;
    float n1y = s*a0.y + c*a1.y;
    a0.x = n0x; a0.y = n0y; a1.x = n1x; a1.y = n1y;
}

#define FOR_PAIRS4(RB, STMT) do {                                     \
    const int msk_ = 1 << (RB);                                       \
    _Pragma("unroll")                                                 \
    for (int h_ = 0; h_ < 8; ++h_) {                                  \
        const int i0 = ((h_ & ~(msk_ - 1)) << 1) | (h_ & (msk_ - 1)); \
        const int i1 = i0 | msk_;                                     \
        STMT;                                                         \
    } } while (0)

// swizzled LDS element addresses (t = threadIdx.x, r = reg index)
#define ADDR_A(r) (((r) << 8) | (t & 0xF0) | ((t ^ (t >> 4) ^ (r)) & 15))
#define ADDR_B(r) (((t >> 4) << 8) | ((r) << 4) | ((t ^ (r) ^ (t >> 4)) & 15))
#define ADDR_C(r) ((t << 4) | (((r) ^ t ^ (t >> 4)) & 15))

__global__ __launch_bounds__(TPB, 4) void vqc_kernel(
    const float* __restrict__ x,    // [B, 12]
    const float* __restrict__ th,   // [2, 12, 2]
    const float* __restrict__ lm,   // [2, 12]
    float* __restrict__ out)        // [B, 12]
{
    __shared__ float2 S[4096];
    __shared__ float red[4 * NQ];

    const int b = blockIdx.x;
    const int t = threadIdx.x;
    const int l = t & 63;
    const int w = t >> 6;

    float2 v[16];

    // ---- layer-0 RX angles ----
    float c0[NQ], s0[NQ];
#pragma unroll
    for (int q = 0; q < NQ; ++q) {
        float h = 0.5f * lm[q] * x[b * NQ + q];
        __sincosf(h, &s0[q], &c0[q]);
    }

    // ---- init in layout A, layer-0 ring folded via inverse perm ----
    // i_p = j_p^j_{p+1} (p<=9), i_10 = j_10^j_0^j_11, i_11 = j_0^j_11
    // j = (r<<8)|t : bits 0..7 = t, 8..11 = r
    //   p=0..6: i_p = t_p^t_{p+1}; i_7 = t_7^r_0; i_8 = r_0^r_1;
    //   i_9 = r_1^r_2; i_10 = r_2^r_3^t_0; i_11 = r_3^t_0
    const int g = (t ^ (t >> 1)) & 0x7F;
    float Pt = 1.0f;
#pragma unroll
    for (int p = 0; p < 7; ++p)
        Pt *= ((g >> p) & 1) ? s0[11 - p] : c0[11 - p];   // qubit 11-p
    const int ct = __popc(g);
    const int n7 = (t >> 7) & 1, n0 = t & 1;
    const float a7  = n7 ? s0[4] : c0[4];   // qubit 4 factor, r0=0
    const float a7x = n7 ? c0[4] : s0[4];   //                r0=1
    const float a10 = n0 ? s0[1] : c0[1];   // qubit 1, (r2^r3)=0
    const float a10x= n0 ? c0[1] : s0[1];
    const float a11 = n0 ? s0[0] : c0[0];   // qubit 0, r3=0
    const float a11x= n0 ? c0[0] : s0[0];
    float F89[4];                           // [(i8<<1)|i9] qubit3*qubit2
    F89[0] = c0[3] * c0[2]; F89[1] = c0[3] * s0[2];
    F89[2] = s0[3] * c0[2]; F89[3] = s0[3] * s0[2];

#pragma unroll
    for (int r = 0; r < 16; ++r) {
        const int r0 = r & 1, r1 = (r >> 1) & 1, r2 = (r >> 2) & 1, r3 = r >> 3;
        const int i8 = r0 ^ r1, i9 = r1 ^ r2;
        float m = Pt * (r0 ? a7x : a7) * F89[(i8 << 1) | i9]
                     * ((r2 ^ r3) ? a10x : a10) * (r3 ? a11x : a11);
        int k = (ct + (n7 ^ r0) + i8 + i9 + (n0 ^ r2 ^ r3) + (n0 ^ r3)) & 3;
        v[r].x = (k == 0) ? m : ((k == 2) ? -m : 0.0f);
        v[r].y = (k == 3) ? m : ((k == 1) ? -m : 0.0f);
    }

    // ---- layer-0 fused RZ*RY ----
#define G_GATE(q, RB) do {                                                \
        float hy = 0.5f * th[(q) * 2 + 0];                                \
        float hz = 0.5f * th[(q) * 2 + 1];                                \
        float cy, sy, cz, sz;                                             \
        __sincosf(hy, &sy, &cy);                                          \
        __sincosf(hz, &sz, &cz);                                          \
        float g00x =  cz * cy, g00y = -sz * cy;                           \
        float g01x = -cz * sy, g01y =  sz * sy;                           \
        float g10x =  cz * sy, g10y =  sz * sy;                           \
        float g11x =  cz * cy, g11y =  sz * cy;                           \
        FOR_PAIRS4(RB, g_fused(v[i0], v[i1], g00x, g00y, g01x, g01y,      \
                               g10x, g10y, g11x, g11y));                  \
    } while (0)

#pragma unroll
    for (int q = 0; q < 4; ++q) G_GATE(q, 3 - q);          // in A

#pragma unroll
    for (int r = 0; r < 16; ++r) S[ADDR_A(r)] = v[r];      // T1: A -> B
    __syncthreads();
#pragma unroll
    for (int r = 0; r < 16; ++r) v[r] = S[ADDR_B(r)];
    __syncthreads();

#pragma unroll
    for (int q = 4; q < 8; ++q) G_GATE(q, 7 - q);          // in B

#pragma unroll
    for (int r = 0; r < 16; ++r) S[ADDR_B(r)] = v[r];      // T2: B -> C
    __syncthreads();
#pragma unroll
    for (int r = 0; r < 16; ++r) v[r] = S[ADDR_C(r)];
    __syncthreads();

#pragma unroll
    for (int q = 8; q < 12; ++q) G_GATE(q, 11 - q);        // in C

    // ---- layer-1 RX ----
#define RX_GATE(q, RB) do {                                               \
        float h = 0.5f * lm[NQ + (q)] * x[b * NQ + (q)];                  \
        float c, s;                                                       \
        __sincosf(h, &s, &c);                                             \
        FOR_PAIRS4(RB, g_rx(v[i0], v[i1], c, s));                         \
    } while (0)

#pragma unroll
    for (int q = 8; q < 12; ++q) RX_GATE(q, 11 - q);       // in C

#pragma unroll
    for (int r = 0; r < 16; ++r) S[ADDR_C(r)] = v[r];      // T3: C -> B
    __syncthreads();
#pragma unroll
    for (int r = 0; r < 16; ++r) v[r] = S[ADDR_B(r)];
    __syncthreads();

#pragma unroll
    for (int q = 4; q < 8; ++q) RX_GATE(q, 7 - q);         // in B

#pragma unroll
    for (int r = 0; r < 16; ++r) S[ADDR_B(r)] = v[r];      // T4: B -> A
    __syncthreads();
#pragma unroll
    for (int r = 0; r < 16; ++r) v[r] = S[ADDR_A(r)];
    __syncthreads();

#pragma unroll
    for (int q = 0; q < 4; ++q) RX_GATE(q, 3 - q);         // in A

    // ---- layer-1 ring: scatter perm(j), land in C ----
#pragma unroll
    for (int r = 0; r < 16; ++r) {
        int j = (r << 8) | t;
        int y = j ^ (j >> 1); y ^= y >> 2; y ^= y >> 4; y ^= y >> 8;
        int p = (y & 0x7FF) | (((__popc(j) ^ (j >> 11)) & 1) << 11);
        int ad = (p & ~15) | ((p ^ (p >> 4) ^ (p >> 8)) & 15);
        S[ad] = v[r];
    }
    __syncthreads();
#pragma unroll
    for (int r = 0; r < 16; ++r) v[r] = S[ADDR_C(r)];
    __syncthreads();

    // ---- layer-1 RY (final RZ dropped: phase-only) ----
#define RY_GATE(q, RB) do {                                               \
        float hy = 0.5f * th[24 + (q) * 2 + 0];                           \
        float cy, sy;                                                     \
        __sincosf(hy, &sy, &cy);                                          \
        FOR_PAIRS4(RB, g_ry(v[i0], v[i1], cy, sy));                       \
    } while (0)

#pragma unroll
    for (int q = 8; q < 12; ++q) RY_GATE(q, 11 - q);       // in C

#pragma unroll
    for (int r = 0; r < 16; ++r) S[ADDR_C(r)] = v[r];      // T6: C -> B
    __syncthreads();
#pragma unroll
    for (int r = 0; r < 16; ++r) v[r] = S[ADDR_B(r)];
    __syncthreads();

#pragma unroll
    for (int q = 4; q < 8; ++q) RY_GATE(q, 7 - q);         // in B

#pragma unroll
    for (int r = 0; r < 16; ++r) S[ADDR_B(r)] = v[r];      // T7: B -> A
    __syncthreads();
#pragma unroll
    for (int r = 0; r < 16; ++r) v[r] = S[ADDR_A(r)];
    __syncthreads();

#pragma unroll
    for (int q = 0; q < 4; ++q) RY_GATE(q, 3 - q);         // in A

    // ---- measurement in A: qubits 0..3 from r bits, 4..11 from t bits ----
    float ptot = 0.0f;
    float zb[4] = {0.f, 0.f, 0.f, 0.f};
#pragma unroll
    for (int r = 0; r < 16; ++r) {
        float p = v[r].x * v[r].x + v[r].y * v[r].y;
        ptot += p;
#pragma unroll
        for (int q = 0; q < 4; ++q)
            zb[q] += ((r >> (3 - q)) & 1) ? -p : p;   // compile-time signs
    }
    float tv[NQ];
#pragma unroll
    for (int q = 0; q < 4; ++q) tv[q] = zb[q];
#pragma unroll
    for (int q = 4; q < 12; ++q)
        tv[q] = ((t >> (11 - q)) & 1) ? -ptot : ptot;

#pragma unroll
    for (int q = 0; q < NQ; ++q) {
#pragma unroll
        for (int m = 1; m < 64; m <<= 1)
            tv[q] += __shfl_xor(tv[q], m, 64);
    }
    if (l == 0) {
#pragma unroll
        for (int q = 0; q < NQ; ++q) red[w * NQ + q] = tv[q];
    }
    __syncthreads();
    if (t < NQ)
        out[b * NQ + t] = red[t] + red[NQ + t] + red[2 * NQ + t] + red[3 * NQ + t];
}

extern "C" void kernel_launch(void* const* d_in, const int* in_sizes, int n_in,
                              void* d_out, int out_size, void* d_ws, size_t ws_size,
                              hipStream_t stream) {
    const int B = in_sizes[0] / NQ;  // 1024
    vqc_kernel<<<B, TPB, 0, stream>>>((const float*)d_in[0],
                                      (const float*)d_in[1],
                                      (const float*)d_in[2],
                                      (float*)d_out);
}

// Round 5
// 87.740 us; speedup vs baseline: 1.0740x; 1.0740x over previous
//
#include <hip/hip_runtime.h>
#include <math.h>

#define NQ 12
#define TPB 256

// One 256-thread block (4 waves) per sample. 4096-amp state split 4-way:
// each thread holds v[16] float2. Three register layouts over amp index j
// (qubit q <-> j bit 11-q):
//   A: j = (r<<8)|t              r = j bits  8..11 = qubits 0..3
//   B: j = (thi<<8)|(r<<4)|tlo   r = j bits  4..7  = qubits 4..7
//   C: j = (t<<4)|r              r = j bits  0..3  = qubits 8..11
// LDS holds amp j at phys(j) = (j&~15) | ((j ^ (j>>4) ^ (j>>8)) & 15)
// (XOR swizzle -> all transpose/scatter patterns conflict-free).
// Circuit (after algebraic reduction):
//   init = layer-0 RX product state with ring perm FOLDED (inverse perm),
//   12 fused (phase-reduced) RZ*RY, 12 RX, ring scatter, 12 RY, measure.
// All 60 uniform sincos pairs precomputed ONCE into LDS co[] by threads
// 0..59 (was: every thread computed all 60 -> VGPR pressure + spill in R4).
// Gate matrices are applied with global phase stripped (|amp|^2 output).

__device__ __forceinline__ void g_fused(float2& a0, float2& a1,
                                        float cy, float sy, float cz, float sz)
{
    // (RZ*RY stripped of global phase): n0 = cy a0 - sy a1 (real coeffs),
    // n1 = e^{i*thz} (sy a0 + cy a1)
    float n0x = cy*a0.x - sy*a1.x;
    float n0y = cy*a0.y - sy*a1.y;
    float wx  = sy*a0.x + cy*a1.x;
    float wy  = sy*a0.y + cy*a1.y;
    a0.x = n0x; a0.y = n0y;
    a1.x = cz*wx - sz*wy;
    a1.y = cz*wy + sz*wx;
}

__device__ __forceinline__ void g_rx(float2& a0, float2& a1, float c, float s)
{
    float n0x = c*a0.x + s*a1.y;
    float n0y = c*a0.y - s*a1.x;
    float n1x = c*a1.x + s*a0.y;
    float n1y = c*a1.y - s*a0.x;
    a0.x = n0x; a0.y = n0y; a1.x = n1x; a1.y = n1y;
}

__device__ __forceinline__ void g_ry(float2& a0, float2& a1, float c, float s)
{
    float n0x = c*a0.x - s*a1.x;
    float n0y = c*a0.y - s*a1.y;
    float n1x = s*a0.x + c*a1.x;
    float n1y = s*a0.y + c*a1.y;
    a0.x = n0x; a0.y = n0y; a1.x = n1x; a1.y = n1y;
}

#define FOR_PAIRS4(RB, STMT) do {                                     \
    const int msk_ = 1 << (RB);                                       \
    _Pragma("unroll")                                                 \
    for (int h_ = 0; h_ < 8; ++h_) {                                  \
        const int i0 = ((h_ & ~(msk_ - 1)) << 1) | (h_ & (msk_ - 1)); \
        const int i1 = i0 | msk_;                                     \
        STMT;                                                         \
    } } while (0)

// swizzled LDS element addresses (t = threadIdx.x, r = reg index)
#define ADDR_A(r) (((r) << 8) | (t & 0xF0) | ((t ^ (t >> 4) ^ (r)) & 15))
#define ADDR_B(r) (((t >> 4) << 8) | ((r) << 4) | ((t ^ (r) ^ (t >> 4)) & 15))
#define ADDR_C(r) ((t << 4) | (((r) ^ t ^ (t >> 4)) & 15))

// co[] coefficient table offsets (float2 = (cos, sin))
//  [0..11]  layer-0 RX half-angles     [12..23] layer-1 RX half-angles
//  [24..35] layer-0 RY half-angles     [36..47] layer-0 RZ FULL angles
//  [48..59] layer-1 RY half-angles

__global__ __launch_bounds__(TPB) void vqc_kernel(
    const float* __restrict__ x,    // [B, 12]
    const float* __restrict__ th,   // [2, 12, 2]
    const float* __restrict__ lm,   // [2, 12]
    float* __restrict__ out)        // [B, 12]
{
    __shared__ float2 S[4096];
    __shared__ float2 co[60];

    const int b = blockIdx.x;
    const int t = threadIdx.x;
    const int l = t & 63;
    const int w = t >> 6;

    // ---- cooperative coefficient precompute (60 sincos total, was 60/thread)
    if (t < 60) {
        float h;
        if (t < 12)       h = 0.5f * lm[t] * x[b * NQ + t];
        else if (t < 24)  h = 0.5f * lm[t] * x[b * NQ + (t - 12)];
        else if (t < 36)  h = 0.5f * th[2 * (t - 24)];
        else if (t < 48)  h = th[2 * (t - 36) + 1];
        else              h = 0.5f * th[24 + 2 * (t - 48)];
        float c, s;
        __sincosf(h, &s, &c);
        co[t].x = c; co[t].y = s;
    }
    __syncthreads();

    float2 v[16];

    // ---- init in layout A, layer-0 ring folded via inverse perm ----
    // i_p = j_p^j_{p+1} (p<=9), i_10 = j_10^j_0^j_11, i_11 = j_0^j_11
    // j = (r<<8)|t : bits 0..7 = t, 8..11 = r
    //   p=0..6: i_p = t_p^t_{p+1}; i_7 = t_7^r_0; i_8 = r_0^r_1;
    //   i_9 = r_1^r_2; i_10 = r_2^r_3^t_0; i_11 = r_3^t_0
    {
        const int g = (t ^ (t >> 1)) & 0x7F;
        float Pt = 1.0f;
#pragma unroll
        for (int p = 0; p < 7; ++p) {
            float2 cs = co[11 - p];                 // qubit 11-p (broadcast)
            Pt *= ((g >> p) & 1) ? cs.y : cs.x;
        }
        const int ct = __popc(g);
        const int n7 = (t >> 7) & 1, n0 = t & 1;
        float2 cs4 = co[4], cs3 = co[3], cs2 = co[2], cs1 = co[1], cs0 = co[0];
        const float a7  = n7 ? cs4.y : cs4.x;   // qubit 4 factor, r0=0
        const float a7x = n7 ? cs4.x : cs4.y;   //                r0=1
        const float a10 = n0 ? cs1.y : cs1.x;   // qubit 1, (r2^r3)=0
        const float a10x= n0 ? cs1.x : cs1.y;
        const float a11 = n0 ? cs0.y : cs0.x;   // qubit 0, r3=0
        const float a11x= n0 ? cs0.x : cs0.y;
        float F89[4];                           // [(i8<<1)|i9] qubit3*qubit2
        F89[0] = cs3.x * cs2.x; F89[1] = cs3.x * cs2.y;
        F89[2] = cs3.y * cs2.x; F89[3] = cs3.y * cs2.y;

#pragma unroll
        for (int r = 0; r < 16; ++r) {
            const int r0 = r & 1, r1 = (r >> 1) & 1, r2 = (r >> 2) & 1,
                      r3 = r >> 3;
            const int i8 = r0 ^ r1, i9 = r1 ^ r2;
            float m = Pt * (r0 ? a7x : a7) * F89[(i8 << 1) | i9]
                         * ((r2 ^ r3) ? a10x : a10) * (r3 ? a11x : a11);
            int k = (ct + (n7 ^ r0) + i8 + i9 + (n0 ^ r2 ^ r3) + (n0 ^ r3)) & 3;
            v[r].x = (k == 0) ? m : ((k == 2) ? -m : 0.0f);
            v[r].y = (k == 3) ? m : ((k == 1) ? -m : 0.0f);
        }
    }

    // ---- layer-0 fused RZ*RY ----
#define G_GATE(q, RB) do {                                                \
        float2 csy = co[24 + (q)];                                        \
        float2 csz = co[36 + (q)];                                        \
        FOR_PAIRS4(RB, g_fused(v[i0], v[i1], csy.x, csy.y, csz.x, csz.y));\
    } while (0)

#pragma unroll
    for (int q = 0; q < 4; ++q) G_GATE(q, 3 - q);          // in A

#pragma unroll
    for (int r = 0; r < 16; ++r) S[ADDR_A(r)] = v[r];      // T1: A -> B
    __syncthreads();
#pragma unroll
    for (int r = 0; r < 16; ++r) v[r] = S[ADDR_B(r)];
    __syncthreads();

#pragma unroll
    for (int q = 4; q < 8; ++q) G_GATE(q, 7 - q);          // in B

#pragma unroll
    for (int r = 0; r < 16; ++r) S[ADDR_B(r)] = v[r];      // T2: B -> C
    __syncthreads();
#pragma unroll
    for (int r = 0; r < 16; ++r) v[r] = S[ADDR_C(r)];
    __syncthreads();

#pragma unroll
    for (int q = 8; q < 12; ++q) G_GATE(q, 11 - q);        // in C

    // ---- layer-1 RX ----
#define RX_GATE(q, RB) do {                                               \
        float2 cs = co[12 + (q)];                                         \
        FOR_PAIRS4(RB, g_rx(v[i0], v[i1], cs.x, cs.y));                   \
    } while (0)

#pragma unroll
    for (int q = 8; q < 12; ++q) RX_GATE(q, 11 - q);       // in C

#pragma unroll
    for (int r = 0; r < 16; ++r) S[ADDR_C(r)] = v[r];      // T3: C -> B
    __syncthreads();
#pragma unroll
    for (int r = 0; r < 16; ++r) v[r] = S[ADDR_B(r)];
    __syncthreads();

#pragma unroll
    for (int q = 4; q < 8; ++q) RX_GATE(q, 7 - q);         // in B

#pragma unroll
    for (int r = 0; r < 16; ++r) S[ADDR_B(r)] = v[r];      // T4: B -> A
    __syncthreads();
#pragma unroll
    for (int r = 0; r < 16; ++r) v[r] = S[ADDR_A(r)];
    __syncthreads();

#pragma unroll
    for (int q = 0; q < 4; ++q) RX_GATE(q, 3 - q);         // in A

    // ---- layer-1 ring: scatter perm(j), land in C ----
#pragma unroll
    for (int r = 0; r < 16; ++r) {
        int j = (r << 8) | t;
        int y = j ^ (j >> 1); y ^= y >> 2; y ^= y >> 4; y ^= y >> 8;
        int p = (y & 0x7FF) | (((__popc(j) ^ (j >> 11)) & 1) << 11);
        int ad = (p & ~15) | ((p ^ (p >> 4) ^ (p >> 8)) & 15);
        S[ad] = v[r];
    }
    __syncthreads();
#pragma unroll
    for (int r = 0; r < 16; ++r) v[r] = S[ADDR_C(r)];
    __syncthreads();

    // ---- layer-1 RY (final RZ dropped: phase-only) ----
#define RY_GATE(q, RB) do {                                               \
        float2 cs = co[48 + (q)];                                         \
        FOR_PAIRS4(RB, g_ry(v[i0], v[i1], cs.x, cs.y));                   \
    } while (0)

#pragma unroll
    for (int q = 8; q < 12; ++q) RY_GATE(q, 11 - q);       // in C

#pragma unroll
    for (int r = 0; r < 16; ++r) S[ADDR_C(r)] = v[r];      // T6: C -> B
    __syncthreads();
#pragma unroll
    for (int r = 0; r < 16; ++r) v[r] = S[ADDR_B(r)];
    __syncthreads();

#pragma unroll
    for (int q = 4; q < 8; ++q) RY_GATE(q, 7 - q);         // in B

#pragma unroll
    for (int r = 0; r < 16; ++r) S[ADDR_B(r)] = v[r];      // T7: B -> A
    __syncthreads();
#pragma unroll
    for (int r = 0; r < 16; ++r) v[r] = S[ADDR_A(r)];
    __syncthreads();

#pragma unroll
    for (int q = 0; q < 4; ++q) RY_GATE(q, 3 - q);         // in A

    // ---- measurement in A: qubits 0..3 from r bits, 4..11 from t bits ----
    float ptot = 0.0f;
    float zb[4] = {0.f, 0.f, 0.f, 0.f};
#pragma unroll
    for (int r = 0; r < 16; ++r) {
        float p = v[r].x * v[r].x + v[r].y * v[r].y;
        ptot += p;
#pragma unroll
        for (int q = 0; q < 4; ++q)
            zb[q] += ((r >> (3 - q)) & 1) ? -p : p;   // compile-time signs
    }
    float tv[NQ];
#pragma unroll
    for (int q = 0; q < 4; ++q) tv[q] = zb[q];
#pragma unroll
    for (int q = 4; q < 12; ++q)
        tv[q] = ((t >> (11 - q)) & 1) ? -ptot : ptot;

#pragma unroll
    for (int q = 0; q < NQ; ++q) {
#pragma unroll
        for (int m = 1; m < 64; m <<= 1)
            tv[q] += __shfl_xor(tv[q], m, 64);
    }

    float* red = (float*)S;   // S is dead past this point (barrier above)
    if (l == 0) {
#pragma unroll
        for (int q = 0; q < NQ; ++q) red[w * NQ + q] = tv[q];
    }
    __syncthreads();
    if (t < NQ)
        out[b * NQ + t] = red[t] + red[NQ + t] + red[2 * NQ + t] + red[3 * NQ + t];
}

extern "C" void kernel_launch(void* const* d_in, const int* in_sizes, int n_in,
                              void* d_out, int out_size, void* d_ws, size_t ws_size,
                              hipStream_t stream) {
    const int B = in_sizes[0] / NQ;  // 1024
    vqc_kernel<<<B, TPB, 0, stream>>>((const float*)d_in[0],
                                      (const float*)d_in[1],
                                      (const float*)d_in[2],
                                      (float*)d_out);
}